// Round 2
// baseline (29.401 us; speedup 1.0000x reference)
//
#include <hip/hip_runtime.h>

// ROI max-pooling, TF-style integer binning, matching the JAX reference:
//   h0 = int(H*roi[0]); h1 = int(H*roi[2]); step = int(float(h1-h0)/7)
//   bin i<6: rows [h0+i*step, h0+(i+1)*step); bin 6: [h0+6*step, h1)
//   step==0: bins 0..5 empty (-inf), bin 6 = [h0, h1)
// Output layout: [B, R, 7, 7, C] float32.

#define OUT_H 7
#define OUT_W 7

__global__ __launch_bounds__(64) void roi_pool_kernel(
    const float* __restrict__ fmap,   // [B,H,W,C]
    const float* __restrict__ rois,   // [B,R,4]
    float* __restrict__ out,          // [B,R,7,7,C]
    int B, int H, int W, int C, int R)
{
    const int blk = blockIdx.x;          // ((b*R + r)*49 + bin)
    const int bin = blk % (OUT_H * OUT_W);
    const int br  = blk / (OUT_H * OUT_W);
    const int r   = br % R;
    const int b   = br / R;
    const int oi  = bin / OUT_W;         // output row bin
    const int oj  = bin % OUT_W;         // output col bin

    const float* roi = rois + (size_t)(b * R + r) * 4;
    const float r0 = roi[0], r1 = roi[1], r2 = roi[2], r3 = roi[3];
    // truncation toward zero == astype(int32) for non-negative values
    const int h0 = (int)((float)H * r0);
    const int w0 = (int)((float)W * r1);
    const int h1 = (int)((float)H * r2);
    const int w1 = (int)((float)W * r3);

    const int hstep = (int)((float)(h1 - h0) / (float)OUT_H);
    const int wstep = (int)((float)(w1 - w0) / (float)OUT_W);

    int rlo, rhi, clo, chi;
    if (hstep >= 1) {
        rlo = h0 + oi * hstep;
        rhi = (oi < OUT_H - 1) ? (rlo + hstep) : h1;
    } else {
        // step==0: only the last bin holds the valid rows
        rlo = (oi == OUT_H - 1) ? h0 : 0;
        rhi = (oi == OUT_H - 1) ? h1 : 0;
    }
    if (wstep >= 1) {
        clo = w0 + oj * wstep;
        chi = (oj < OUT_W - 1) ? (clo + wstep) : w1;
    } else {
        clo = (oj == OUT_W - 1) ? w0 : 0;
        chi = (oj == OUT_W - 1) ? w1 : 0;
    }

    const int tid = threadIdx.x;         // 0..63 -> float4 channel group
    const int c4  = C / 4;               // 64 float4 groups

    float4 acc = make_float4(-INFINITY, -INFINITY, -INFINITY, -INFINITY);

    for (int h = rlo; h < rhi; ++h) {
        const float4* rowp =
            (const float4*)(fmap + (size_t)(b * H + h) * W * C);
        for (int w = clo; w < chi; ++w) {
            float4 v = rowp[(size_t)w * c4 + tid];
            acc.x = fmaxf(acc.x, v.x);
            acc.y = fmaxf(acc.y, v.y);
            acc.z = fmaxf(acc.z, v.z);
            acc.w = fmaxf(acc.w, v.w);
        }
    }

    float4* o = (float4*)(out + (size_t)blk * C);
    o[tid] = acc;
}

extern "C" void kernel_launch(void* const* d_in, const int* in_sizes, int n_in,
                              void* d_out, int out_size, void* d_ws, size_t ws_size,
                              hipStream_t stream) {
    const float* fmap = (const float*)d_in[0];
    const float* rois = (const float*)d_in[1];
    float* out = (float*)d_out;

    const int B = 4, H = 56, W = 56, C = 256, R = 64;
    // sanity: in_sizes[0] == B*H*W*C, in_sizes[1] == B*R*4 (fixed by setup_inputs)

    const int nblocks = B * R * OUT_H * OUT_W;   // 12544
    roi_pool_kernel<<<nblocks, 64, 0, stream>>>(fmap, rois, out, B, H, W, C, R);
}

// Round 4
// 19.633 us; speedup vs baseline: 1.4976x; 1.4976x over previous
//
#include <hip/hip_runtime.h>

// ROI max-pooling, TF-style integer binning (matches the JAX reference).
// Round 4: same as R3 (XCD-locality swizzle: image b -> XCD pair {2b,2b+1};
// nontemporal output store) but with clang ext_vector float4 so
// __builtin_nontemporal_store compiles.

#define OUT_H 7
#define OUT_W 7
#define NBIN (OUT_H * OUT_W)   // 49
#define NB 4
#define NR 64
#define NH 56
#define NW 56
#define NC 256

// blocks per image = NR*NBIN = 3136; per XCD = 1568; total = 12544
#define BLKS_PER_XCD_SLOT 1568

typedef float v4f __attribute__((ext_vector_type(4)));

__global__ __launch_bounds__(64) void roi_pool_kernel(
    const float* __restrict__ fmap,   // [B,H,W,C]
    const float* __restrict__ rois,   // [B,R,4]
    float* __restrict__ out)          // [B,R,7,7,C]
{
    // --- XCD-aware decode: blk%8 = xcd; image b = xcd>>1 ---
    const int blk  = blockIdx.x;
    const int xcd  = blk & 7;
    const int b    = xcd >> 1;
    const int work = ((xcd & 1) * BLKS_PER_XCD_SLOT) + (blk >> 3); // [0, 3136)
    const int r    = work / NBIN;
    const int bin  = work - r * NBIN;
    const int oi   = bin / OUT_W;
    const int oj   = bin - oi * OUT_W;

    const float* roi = rois + (size_t)(b * NR + r) * 4;
    const float r0 = roi[0], r1 = roi[1], r2 = roi[2], r3 = roi[3];
    const int h0 = (int)((float)NH * r0);
    const int w0 = (int)((float)NW * r1);
    const int h1 = (int)((float)NH * r2);
    const int w1 = (int)((float)NW * r3);

    const int hstep = (int)((float)(h1 - h0) / (float)OUT_H);
    const int wstep = (int)((float)(w1 - w0) / (float)OUT_W);

    int rlo, rhi, clo, chi;
    if (hstep >= 1) {
        rlo = h0 + oi * hstep;
        rhi = (oi < OUT_H - 1) ? (rlo + hstep) : h1;
    } else {
        rlo = (oi == OUT_H - 1) ? h0 : 0;
        rhi = (oi == OUT_H - 1) ? h1 : 0;
    }
    if (wstep >= 1) {
        clo = w0 + oj * wstep;
        chi = (oj < OUT_W - 1) ? (clo + wstep) : w1;
    } else {
        clo = (oj == OUT_W - 1) ? w0 : 0;
        chi = (oj == OUT_W - 1) ? w1 : 0;
    }

    const int tid = threadIdx.x;          // 0..63 -> float4 channel group
    const int c4  = NC / 4;               // 64

    v4f acc = (v4f){-INFINITY, -INFINITY, -INFINITY, -INFINITY};

    for (int h = rlo; h < rhi; ++h) {
        const v4f* rowp =
            (const v4f*)(fmap + (size_t)(b * NH + h) * NW * NC);
        for (int w = clo; w < chi; ++w) {
            v4f v = rowp[(size_t)w * c4 + tid];
            acc.x = fmaxf(acc.x, v.x);
            acc.y = fmaxf(acc.y, v.y);
            acc.z = fmaxf(acc.z, v.z);
            acc.w = fmaxf(acc.w, v.w);
        }
    }

    // output index uses the LOGICAL block id (b, r, bin), not blockIdx
    const size_t obase = ((size_t)((b * NR + r) * NBIN + bin)) * NC;
    v4f* o = (v4f*)(out + obase);
    __builtin_nontemporal_store(acc, o + tid);
}

extern "C" void kernel_launch(void* const* d_in, const int* in_sizes, int n_in,
                              void* d_out, int out_size, void* d_ws, size_t ws_size,
                              hipStream_t stream) {
    const float* fmap = (const float*)d_in[0];
    const float* rois = (const float*)d_in[1];
    float* out = (float*)d_out;

    const int nblocks = NB * NR * NBIN;   // 12544
    roi_pool_kernel<<<nblocks, 64, 0, stream>>>(fmap, rois, out);
}

// Round 5
// 15.728 us; speedup vs baseline: 1.8694x; 1.2483x over previous
//
#include <hip/hip_runtime.h>

// ROI max-pooling, TF-style integer binning (matches the JAX reference).
// Round 5: 256-thread blocks (4 waves, one bin per wave) to double resident
// waves/CU past the workgroup-slot cap; 2x2-unrolled window loop with 4
// independent accumulators for 4 loads in flight; XCD pinning (image b ->
// XCD pair {2b,2b+1}) + nontemporal output store kept from R4.

#define OUT_H 7
#define OUT_W 7
#define NBIN (OUT_H * OUT_W)   // 49
#define NB 4
#define NR 64
#define NH 56
#define NW 56
#define NC 256
#define C4 (NC / 4)            // 64 float4 groups per pixel

// total bins = 4*64*49 = 12544; 4 bins/block -> 3136 blocks
// per image 784 blocks; per XCD slot 392
#define BLKS_PER_XCD_SLOT 392

typedef float v4f __attribute__((ext_vector_type(4)));

__device__ __forceinline__ v4f vmax4(v4f a, v4f b) {
    v4f r;
    r.x = fmaxf(a.x, b.x);
    r.y = fmaxf(a.y, b.y);
    r.z = fmaxf(a.z, b.z);
    r.w = fmaxf(a.w, b.w);
    return r;
}

__global__ __launch_bounds__(256) void roi_pool_kernel(
    const float* __restrict__ fmap,   // [B,H,W,C]
    const float* __restrict__ rois,   // [B,R,4]
    float* __restrict__ out)          // [B,R,7,7,C]
{
    const int blk  = blockIdx.x;
    const int xcd  = blk & 7;          // image b -> XCDs {2b, 2b+1}
    const int b    = xcd >> 1;
    const int wid  = threadIdx.x >> 6; // wave id 0..3 -> bin within group
    const int lane = threadIdx.x & 63; // float4 channel group

    const int work = ((xcd & 1) * BLKS_PER_XCD_SLOT) + (blk >> 3); // [0,784)
    const int gbin = work * 4 + wid;   // [0, 3136) bin id within image
    const int r    = gbin / NBIN;
    const int bin  = gbin - r * NBIN;
    const int oi   = bin / OUT_W;
    const int oj   = bin - oi * OUT_W;

    const float* roi = rois + (size_t)(b * NR + r) * 4;
    const float r0 = roi[0], r1 = roi[1], r2 = roi[2], r3 = roi[3];
    const int h0 = (int)((float)NH * r0);
    const int w0 = (int)((float)NW * r1);
    const int h1 = (int)((float)NH * r2);
    const int w1 = (int)((float)NW * r3);

    const int hstep = (int)((float)(h1 - h0) / (float)OUT_H);
    const int wstep = (int)((float)(w1 - w0) / (float)OUT_W);

    int rlo, rhi, clo, chi;
    if (hstep >= 1) {
        rlo = h0 + oi * hstep;
        rhi = (oi < OUT_H - 1) ? (rlo + hstep) : h1;
    } else {
        rlo = (oi == OUT_H - 1) ? h0 : 0;
        rhi = (oi == OUT_H - 1) ? h1 : 0;
    }
    if (wstep >= 1) {
        clo = w0 + oj * wstep;
        chi = (oj < OUT_W - 1) ? (clo + wstep) : w1;
    } else {
        clo = (oj == OUT_W - 1) ? w0 : 0;
        chi = (oj == OUT_W - 1) ? w1 : 0;
    }

    const v4f* base =
        (const v4f*)(fmap + (size_t)b * NH * NW * NC) + lane;
    // pixel (h,w): base[(h*NW + w)*C4]

    const v4f ninf = (v4f){-INFINITY, -INFINITY, -INFINITY, -INFINITY};
    v4f acc0 = ninf, acc1 = ninf, acc2 = ninf, acc3 = ninf;

    int h = rlo;
    for (; h + 1 < rhi; h += 2) {
        const v4f* r0p = base + (size_t)(h * NW) * C4;
        const v4f* r1p = r0p + (size_t)NW * C4;
        int w = clo;
        for (; w + 1 < chi; w += 2) {
            v4f a = r0p[(size_t)w * C4];
            v4f bb = r0p[(size_t)(w + 1) * C4];
            v4f c = r1p[(size_t)w * C4];
            v4f d = r1p[(size_t)(w + 1) * C4];
            acc0 = vmax4(acc0, a);
            acc1 = vmax4(acc1, bb);
            acc2 = vmax4(acc2, c);
            acc3 = vmax4(acc3, d);
        }
        if (w < chi) {
            v4f a = r0p[(size_t)w * C4];
            v4f c = r1p[(size_t)w * C4];
            acc0 = vmax4(acc0, a);
            acc2 = vmax4(acc2, c);
        }
    }
    if (h < rhi) {
        const v4f* r0p = base + (size_t)(h * NW) * C4;
        int w = clo;
        for (; w + 1 < chi; w += 2) {
            v4f a = r0p[(size_t)w * C4];
            v4f bb = r0p[(size_t)(w + 1) * C4];
            acc0 = vmax4(acc0, a);
            acc1 = vmax4(acc1, bb);
        }
        if (w < chi) acc0 = vmax4(acc0, r0p[(size_t)w * C4]);
    }

    v4f acc = vmax4(vmax4(acc0, acc1), vmax4(acc2, acc3));

    // output index uses the LOGICAL ids (b, r, bin), not blockIdx
    const size_t obase = ((size_t)((b * NR + r) * NBIN + bin)) * NC;
    v4f* o = (v4f*)(out + obase);
    __builtin_nontemporal_store(acc, o + lane);
}

extern "C" void kernel_launch(void* const* d_in, const int* in_sizes, int n_in,
                              void* d_out, int out_size, void* d_ws, size_t ws_size,
                              hipStream_t stream) {
    const float* fmap = (const float*)d_in[0];
    const float* rois = (const float*)d_in[1];
    float* out = (float*)d_out;

    const int nblocks = NB * NR * NBIN / 4;   // 3136
    roi_pool_kernel<<<nblocks, 256, 0, stream>>>(fmap, rois, out);
}